// Round 1
// baseline (3370.700 us; speedup 1.0000x reference)
//
#include <hip/hip_runtime.h>

#define N_TOTAL (8 * 32768)   // 262144 rows
#define D 128
#define K 1024
#define DECAY 0.8f
#define EPS 1e-7f

// ---------------------------------------------------------------------------
// K0: e2h[c] = 0.5 * sum_d embed[c][d]^2
// argmax_k -(f2 - 2 x.e + e2)  ==  argmax_k (x.e - e2/2)
// ---------------------------------------------------------------------------
__global__ void k_e2(const float* __restrict__ embed, float* __restrict__ e2h) {
    int c = blockIdx.x * blockDim.x + threadIdx.x;
    if (c >= K) return;
    const float* e = embed + (size_t)c * D;
    float s = 0.f;
#pragma unroll
    for (int d = 0; d < D; d += 4) {
        float4 v = *(const float4*)(e + d);
        s += v.x * v.x + v.y * v.y + v.z * v.z + v.w * v.w;
    }
    e2h[c] = 0.5f * s;
}

// ---------------------------------------------------------------------------
// K1: per-row argmax of (x . e_k - e2h[k]) over all K codes.
// Tiled fp32 GEMM-like: 64 rows x 64 codes per block, 4x4 per thread.
// ---------------------------------------------------------------------------
#define BM 64
#define BN 64
#define LPAD 132   // 128+4 floats: float4-aligned, row stride 132%32=4 banks

__global__ __launch_bounds__(256) void k_argmax(
    const float* __restrict__ x, const float* __restrict__ embed,
    const float* __restrict__ e2h, unsigned int* __restrict__ ind) {
    __shared__ float xs[BM][LPAD];
    __shared__ float es[BN][LPAD];
    __shared__ float e2s[BN];
    __shared__ float rvals[BM][16];
    __shared__ unsigned int ridx[BM][16];

    int tid = threadIdx.x;
    int tx = tid & 15, ty = tid >> 4;
    size_t row0 = (size_t)blockIdx.x * BM;

    // stage x tile (64 x 128)
    for (int i = tid; i < BM * (D / 4); i += 256) {
        int r = i >> 5;
        int d4 = (i & 31) << 2;
        *(float4*)&xs[r][d4] = *(const float4*)&x[(row0 + r) * D + d4];
    }

    float best[4];
    unsigned int bidx[4];
#pragma unroll
    for (int i = 0; i < 4; i++) { best[i] = -1e30f; bidx[i] = 0u; }

    for (int ct = 0; ct < K / BN; ct++) {
        __syncthreads();  // protect es (and cover xs staging on first iter)
        for (int i = tid; i < BN * (D / 4); i += 256) {
            int r = i >> 5;
            int d4 = (i & 31) << 2;
            *(float4*)&es[r][d4] =
                *(const float4*)&embed[(size_t)(ct * BN + r) * D + d4];
        }
        if (tid < BN) e2s[tid] = e2h[ct * BN + tid];
        __syncthreads();

        float acc[4][4];
#pragma unroll
        for (int i = 0; i < 4; i++)
#pragma unroll
            for (int j = 0; j < 4; j++) acc[i][j] = 0.f;

#pragma unroll 4
        for (int kk = 0; kk < D; kk += 4) {
            float4 a[4], b[4];
#pragma unroll
            for (int i = 0; i < 4; i++) a[i] = *(const float4*)&xs[tx + 16 * i][kk];
#pragma unroll
            for (int j = 0; j < 4; j++) b[j] = *(const float4*)&es[ty + 16 * j][kk];
#pragma unroll
            for (int i = 0; i < 4; i++)
#pragma unroll
                for (int j = 0; j < 4; j++)
                    acc[i][j] += a[i].x * b[j].x + a[i].y * b[j].y +
                                 a[i].z * b[j].z + a[i].w * b[j].w;
        }

#pragma unroll
        for (int i = 0; i < 4; i++) {
#pragma unroll
            for (int j = 0; j < 4; j++) {
                int cl = ty + 16 * j;
                float s = acc[i][j] - e2s[cl];
                unsigned int cg = (unsigned int)(ct * BN + cl);
                if (s > best[i]) { best[i] = s; bidx[i] = cg; }
            }
        }
    }

    // reduce the 16 per-ty partials for each row (codes disjoint across ty)
#pragma unroll
    for (int i = 0; i < 4; i++) {
        rvals[tx + 16 * i][ty] = best[i];
        ridx[tx + 16 * i][ty] = bidx[i];
    }
    __syncthreads();
    if (tid < BM) {
        float bv = rvals[tid][0];
        unsigned int bi = ridx[tid][0];
        for (int t = 1; t < 16; t++) {
            float v = rvals[tid][t];
            unsigned int ii = ridx[tid][t];
            if (v > bv || (v == bv && ii < bi)) { bv = v; bi = ii; }
        }
        ind[row0 + tid] = bi;
    }
}

// ---------------------------------------------------------------------------
// K2: quantize[n][:] = embed[ind[n]][:]
// ---------------------------------------------------------------------------
__global__ __launch_bounds__(256) void k_quant(
    const unsigned int* __restrict__ ind, const float* __restrict__ embed,
    float* __restrict__ q) {
    size_t gid = (size_t)blockIdx.x * 256 + threadIdx.x;  // N*32 threads
    size_t n = gid >> 5;
    int d4 = (int)(gid & 31) << 2;
    unsigned int c = ind[n];
    *(float4*)&q[n * D + d4] = *(const float4*)&embed[(size_t)c * D + d4];
}

// ---------------------------------------------------------------------------
// K3: counts + segment sums -> ema_num_new, ema_embed_new.
// 256 blocks; block b owns codes [4b, 4b+4). Scans ind in chunks, queues
// matching rows in LDS, accumulates coalesced row reads into registers.
// No global atomics; each block exclusively writes its 4 codes.
// ---------------------------------------------------------------------------
#define CPB 4
#define CHUNK 8192

__global__ __launch_bounds__(256) void k_ema(
    const unsigned int* __restrict__ ind, const float* __restrict__ x,
    const float* __restrict__ ema_num, const float* __restrict__ ema_embed,
    float* __restrict__ ema_num_new, float* __restrict__ ema_embed_new) {
    __shared__ unsigned int q[CHUNK];
    __shared__ int qn;
    __shared__ float sums[CPB][D];
    __shared__ float cnt[CPB];

    int tid = threadIdx.x;
    unsigned int myblk = blockIdx.x;
    int c0 = myblk * CPB;
    int d = tid & 127;
    int h = tid >> 7;  // 0 or 1

    float racc[CPB];
    float ccnt[CPB];
#pragma unroll
    for (int c = 0; c < CPB; c++) { racc[c] = 0.f; ccnt[c] = 0.f; }

    for (int base = 0; base < N_TOTAL; base += CHUNK) {
        if (tid == 0) qn = 0;
        __syncthreads();
        for (int i = tid; i < CHUNK; i += 256) {
            unsigned int v = ind[base + i];
            if ((v >> 2) == myblk) {
                int p = atomicAdd(&qn, 1);
                q[p] = ((unsigned int)(base + i) << 2) | (v & 3u);
                ccnt[v & 3u] += 1.f;
            }
        }
        __syncthreads();
        int nq = qn;
        for (int j = h; j < nq; j += 2) {
            unsigned int e = q[j];
            int c = e & 3;
            size_t row = e >> 2;
            racc[c] += x[row * D + d];
        }
        __syncthreads();
    }

    // combine the two halves (h=0 writes, h=1 adds)
    if (h == 0) {
#pragma unroll
        for (int c = 0; c < CPB; c++) sums[c][d] = racc[c];
    }
    __syncthreads();
    if (h == 1) {
#pragma unroll
        for (int c = 0; c < CPB; c++) sums[c][d] += racc[c];
    }
    if (tid < CPB) cnt[tid] = 0.f;
    __syncthreads();
#pragma unroll
    for (int c = 0; c < CPB; c++)
        if (ccnt[c] != 0.f) atomicAdd(&cnt[c], ccnt[c]);
    __syncthreads();

    if (tid < CPB) {
        int k = c0 + tid;
        ema_num_new[k] = DECAY * ema_num[k] + (1.0f - DECAY) * cnt[tid];
    }
    for (int i = tid; i < CPB * D; i += 256) {
        int c = i >> 7, dd = i & 127;
        size_t k = (size_t)(c0 + c) * D + dd;
        ema_embed_new[k] = DECAY * ema_embed[k] + (1.0f - DECAY) * sums[c][dd];
    }
}

// ---------------------------------------------------------------------------
// K4: total = sum(ema_num_new); denom[k] = (v+EPS)/(total+K*EPS)*total
// ---------------------------------------------------------------------------
__global__ __launch_bounds__(1024) void k_denom(
    const float* __restrict__ ema_num_new, float* __restrict__ denom) {
    __shared__ float red[16];
    int tid = threadIdx.x;
    float v = ema_num_new[tid];
    float s = v;
    for (int off = 32; off; off >>= 1) s += __shfl_down(s, off, 64);
    if ((tid & 63) == 0) red[tid >> 6] = s;
    __syncthreads();
    if (tid < 16) {
        float t = red[tid];
        for (int off = 8; off; off >>= 1) t += __shfl_down(t, off, 16);
        if (tid == 0) red[0] = t;
    }
    __syncthreads();
    float total = red[0];
    denom[tid] = (v + EPS) / (total + (float)K * EPS) * total;
}

// ---------------------------------------------------------------------------
// K5: embed_new = ema_embed_new / denom[k]
// ---------------------------------------------------------------------------
__global__ __launch_bounds__(256) void k_embednew(
    const float* __restrict__ ema_embed_new, const float* __restrict__ denom,
    float* __restrict__ embed_new) {
    int gid = blockIdx.x * 256 + threadIdx.x;  // K*D/4 threads
    int k = gid >> 5;
    int d4 = (gid & 31) << 2;
    float4 v = *(const float4*)&ema_embed_new[(size_t)k * D + d4];
    float s = denom[k];
    float4 o;
    o.x = v.x / s; o.y = v.y / s; o.z = v.z / s; o.w = v.w / s;
    *(float4*)&embed_new[(size_t)k * D + d4] = o;
}

// ---------------------------------------------------------------------------
extern "C" void kernel_launch(void* const* d_in, const int* in_sizes, int n_in,
                              void* d_out, int out_size, void* d_ws,
                              size_t ws_size, hipStream_t stream) {
    const float* x = (const float*)d_in[0];
    const float* embed = (const float*)d_in[1];
    const float* ema_embed = (const float*)d_in[2];
    const float* ema_num = (const float*)d_in[3];

    float* out = (float*)d_out;
    float* quantize = out;                                   // N*D
    float* embed_new = out + (size_t)N_TOTAL * D;            // K*D
    float* ema_num_new = embed_new + (size_t)K * D;          // K
    float* ema_embed_new = ema_num_new + K;                  // K*D

    unsigned int* ind = (unsigned int*)d_ws;                 // N u32
    float* e2h = (float*)((char*)d_ws + (size_t)N_TOTAL * sizeof(unsigned int));
    float* denom = e2h + K;

    k_e2<<<K / 256, 256, 0, stream>>>(embed, e2h);
    k_argmax<<<N_TOTAL / BM, 256, 0, stream>>>(x, embed, e2h, ind);
    k_quant<<<(N_TOTAL * 32) / 256, 256, 0, stream>>>(ind, embed, quantize);
    k_ema<<<K / CPB, 256, 0, stream>>>(ind, x, ema_num, ema_embed,
                                       ema_num_new, ema_embed_new);
    k_denom<<<1, K, 0, stream>>>(ema_num_new, denom);
    k_embednew<<<(K * D / 4) / 256, 256, 0, stream>>>(ema_embed_new, denom,
                                                      embed_new);
}

// Round 4
// 2003.498 us; speedup vs baseline: 1.6824x; 1.6824x over previous
//
#include <hip/hip_runtime.h>

#define N_TOTAL (8 * 32768)   // 262144 rows
#define D 128
#define K 1024
#define DECAY 0.8f
#define EPS 1e-7f

// ---------------------------------------------------------------------------
// K0: e2h[c] = 0.5 * sum_d embed[c][d]^2
// argmax_k -(f2 - 2 x.e + e2)  ==  argmax_k (x.e - e2/2)
// ---------------------------------------------------------------------------
__global__ void k_e2(const float* __restrict__ embed, float* __restrict__ e2h) {
    int c = blockIdx.x * blockDim.x + threadIdx.x;
    if (c >= K) return;
    const float* e = embed + (size_t)c * D;
    float s = 0.f;
#pragma unroll
    for (int d = 0; d < D; d += 4) {
        float4 v = *(const float4*)(e + d);
        s += v.x * v.x + v.y * v.y + v.z * v.z + v.w * v.w;
    }
    e2h[c] = 0.5f * s;
}

// ---------------------------------------------------------------------------
// K1: per-row argmax of (x . e_k - e2h[k]) over all K codes.
// 128x128 tile per block (256 threads, 8x8 per thread), BK=32 LDS chunks.
// Padded LDS rows (36 floats): a-reads 2-way aliased (free), b-reads clean.
// ---------------------------------------------------------------------------
#define BM 128
#define BN 128
#define BKC 32
#define LP (BKC + 4)   // 36 floats row stride

__global__ __launch_bounds__(256) void k_argmax(
    const float* __restrict__ x, const float* __restrict__ embed,
    const float* __restrict__ e2h, unsigned int* __restrict__ ind) {
    __shared__ float xs[BM][LP];
    __shared__ float es[BN][LP];
    __shared__ float e2s[BN];

    int tid = threadIdx.x;
    int tx = tid & 15, ty = tid >> 4;
    size_t row0 = (size_t)blockIdx.x * BM;

    float best[8];
    unsigned int bidx[8];
#pragma unroll
    for (int i = 0; i < 8; i++) { best[i] = -1e30f; bidx[i] = 0u; }

    for (int ct = 0; ct < K / BN; ct++) {
        float acc[8][8];
#pragma unroll
        for (int i = 0; i < 8; i++)
#pragma unroll
            for (int j = 0; j < 8; j++) acc[i][j] = 0.f;

        for (int kb = 0; kb < D; kb += BKC) {
            __syncthreads();  // protect LDS from previous phase's readers
            for (int i = tid; i < BM * (BKC / 4); i += 256) {
                int r = i >> 3;
                int c4 = (i & 7) << 2;
                *(float4*)&xs[r][c4] =
                    *(const float4*)&x[(row0 + r) * D + kb + c4];
            }
            for (int i = tid; i < BN * (BKC / 4); i += 256) {
                int r = i >> 3;
                int c4 = (i & 7) << 2;
                *(float4*)&es[r][c4] =
                    *(const float4*)&embed[(size_t)(ct * BN + r) * D + kb + c4];
            }
            if (kb == 0 && tid < BN) e2s[tid] = e2h[ct * BN + tid];
            __syncthreads();

            for (int kk = 0; kk < BKC; kk += 4) {
                float4 a[8], b[8];
#pragma unroll
                for (int i = 0; i < 8; i++)
                    a[i] = *(const float4*)&xs[tx + 16 * i][kk];
#pragma unroll
                for (int j = 0; j < 8; j++)
                    b[j] = *(const float4*)&es[ty + 16 * j][kk];
#pragma unroll
                for (int i = 0; i < 8; i++)
#pragma unroll
                    for (int j = 0; j < 8; j++)
                        acc[i][j] += a[i].x * b[j].x + a[i].y * b[j].y +
                                     a[i].z * b[j].z + a[i].w * b[j].w;
            }
        }

#pragma unroll
        for (int j = 0; j < 8; j++) {
            int cl = ty + 16 * j;
            float e2v = e2s[cl];
            unsigned int cg = (unsigned int)(ct * BN + cl);
#pragma unroll
            for (int i = 0; i < 8; i++) {
                float s = acc[i][j] - e2v;
                if (s > best[i]) { best[i] = s; bidx[i] = cg; }
            }
        }
    }

    // cross-thread reduce: 16 candidates per row, alias reduction LDS onto xs/es
    float (*rvals)[16] = (float (*)[16])xs;          // 128*16 floats < xs size
    unsigned int (*ridx)[16] = (unsigned int (*)[16])es;
    __syncthreads();
#pragma unroll
    for (int i = 0; i < 8; i++) {
        rvals[tx + 16 * i][ty] = best[i];
        ridx[tx + 16 * i][ty] = bidx[i];
    }
    __syncthreads();
    if (tid < BM) {
        float bv = rvals[tid][0];
        unsigned int bi = ridx[tid][0];
        for (int t = 1; t < 16; t++) {
            float v = rvals[tid][t];
            unsigned int ii = ridx[tid][t];
            if (v > bv || (v == bv && ii < bi)) { bv = v; bi = ii; }
        }
        ind[row0 + tid] = bi;
    }
}

// ---------------------------------------------------------------------------
// K2: quantize[n][:] = embed[ind[n]][:]
// ---------------------------------------------------------------------------
__global__ __launch_bounds__(256) void k_quant(
    const unsigned int* __restrict__ ind, const float* __restrict__ embed,
    float* __restrict__ q) {
    size_t gid = (size_t)blockIdx.x * 256 + threadIdx.x;  // N*32 threads
    size_t n = gid >> 5;
    int d4 = (int)(gid & 31) << 2;
    unsigned int c = ind[n];
    *(float4*)&q[n * D + d4] = *(const float4*)&embed[(size_t)c * D + d4];
}

// ---------------------------------------------------------------------------
// EMA pipeline: zero -> count -> scan -> scatter -> sum
// ---------------------------------------------------------------------------
__global__ __launch_bounds__(256) void k_zero(unsigned int* __restrict__ counts,
                                              unsigned int* __restrict__ cursor) {
    int i = blockIdx.x * 256 + threadIdx.x;
    if (i < K) { counts[i] = 0u; cursor[i] = 0u; }
}

// 256 blocks x 256 threads, 4 entries/thread: LDS histogram then global adds.
__global__ __launch_bounds__(256) void k_count(
    const unsigned int* __restrict__ ind, unsigned int* __restrict__ counts) {
    __shared__ unsigned int hist[K];
    int tid = threadIdx.x;
    for (int i = tid; i < K; i += 256) hist[i] = 0u;
    __syncthreads();
    int base = blockIdx.x * 1024;
#pragma unroll
    for (int j = 0; j < 4; j++)
        atomicAdd(&hist[ind[base + j * 256 + tid]], 1u);
    __syncthreads();
    for (int i = tid; i < K; i += 256) {
        unsigned int h = hist[i];
        if (h) atomicAdd(&counts[i], h);
    }
}

// single block, K threads: exclusive scan
__global__ __launch_bounds__(1024) void k_scan(
    const unsigned int* __restrict__ counts, unsigned int* __restrict__ offsets,
    unsigned int* __restrict__ cursor) {
    __shared__ unsigned int tmp[K];
    int tid = threadIdx.x;
    unsigned int v = counts[tid];
    tmp[tid] = v;
    __syncthreads();
    for (int off = 1; off < K; off <<= 1) {
        unsigned int t = (tid >= off) ? tmp[tid - off] : 0u;
        __syncthreads();
        tmp[tid] += t;
        __syncthreads();
    }
    unsigned int excl = tmp[tid] - v;
    offsets[tid] = excl;
    cursor[tid] = excl;
}

__global__ __launch_bounds__(256) void k_scatter(
    const unsigned int* __restrict__ ind, unsigned int* __restrict__ cursor,
    unsigned int* __restrict__ bucket) {
    unsigned int n = blockIdx.x * 256 + threadIdx.x;
    unsigned int c = ind[n];
    unsigned int pos = atomicAdd(&cursor[c], 1u);
    bucket[pos] = n;
}

// one block per code: sum its rows (coalesced 512B reads, row idx wave-uniform)
__global__ __launch_bounds__(256) void k_sum(
    const unsigned int* __restrict__ bucket,
    const unsigned int* __restrict__ offsets,
    const unsigned int* __restrict__ counts, const float* __restrict__ x,
    const float* __restrict__ ema_num, const float* __restrict__ ema_embed,
    float* __restrict__ ema_num_new, float* __restrict__ ema_embed_new) {
    __shared__ float sums[D];
    int tid = threadIdx.x;
    int c = blockIdx.x;
    int d = tid & 127;
    int h = tid >> 7;  // two rows in flight
    int start = (int)offsets[c];
    int cnt = (int)counts[c];

    float acc = 0.f;
    int j = h;
    for (; j + 8 <= cnt; j += 8) {
        unsigned int r0 = bucket[start + j];
        unsigned int r1 = bucket[start + j + 2];
        unsigned int r2 = bucket[start + j + 4];
        unsigned int r3 = bucket[start + j + 6];
        float v0 = x[(size_t)r0 * D + d];
        float v1 = x[(size_t)r1 * D + d];
        float v2 = x[(size_t)r2 * D + d];
        float v3 = x[(size_t)r3 * D + d];
        acc += v0 + v1 + v2 + v3;
    }
    for (; j < cnt; j += 2) acc += x[(size_t)bucket[start + j] * D + d];

    if (h == 0) sums[d] = acc;
    __syncthreads();
    if (h == 1) sums[d] += acc;
    __syncthreads();

    if (tid < D) {
        size_t k = (size_t)c * D + tid;
        ema_embed_new[k] = DECAY * ema_embed[k] + (1.0f - DECAY) * sums[tid];
    }
    if (tid == 0)
        ema_num_new[c] = DECAY * ema_num[c] + (1.0f - DECAY) * (float)cnt;
}

// ---------------------------------------------------------------------------
// K4: total = sum(ema_num_new); denom[k] = (v+EPS)/(total+K*EPS)*total
// ---------------------------------------------------------------------------
__global__ __launch_bounds__(1024) void k_denom(
    const float* __restrict__ ema_num_new, float* __restrict__ denom) {
    __shared__ float red[16];
    int tid = threadIdx.x;
    float v = ema_num_new[tid];
    float s = v;
    for (int off = 32; off; off >>= 1) s += __shfl_down(s, off, 64);
    if ((tid & 63) == 0) red[tid >> 6] = s;
    __syncthreads();
    if (tid < 16) {
        float t = red[tid];
        for (int off = 8; off; off >>= 1) t += __shfl_down(t, off, 16);
        if (tid == 0) red[0] = t;
    }
    __syncthreads();
    float total = red[0];
    denom[tid] = (v + EPS) / (total + (float)K * EPS) * total;
}

// ---------------------------------------------------------------------------
// K5: embed_new = ema_embed_new / denom[k]
// ---------------------------------------------------------------------------
__global__ __launch_bounds__(256) void k_embednew(
    const float* __restrict__ ema_embed_new, const float* __restrict__ denom,
    float* __restrict__ embed_new) {
    int gid = blockIdx.x * 256 + threadIdx.x;  // K*D/4 threads
    int k = gid >> 5;
    int d4 = (gid & 31) << 2;
    float4 v = *(const float4*)&ema_embed_new[(size_t)k * D + d4];
    float s = denom[k];
    float4 o;
    o.x = v.x / s; o.y = v.y / s; o.z = v.z / s; o.w = v.w / s;
    *(float4*)&embed_new[(size_t)k * D + d4] = o;
}

// ---------------------------------------------------------------------------
extern "C" void kernel_launch(void* const* d_in, const int* in_sizes, int n_in,
                              void* d_out, int out_size, void* d_ws,
                              size_t ws_size, hipStream_t stream) {
    const float* x = (const float*)d_in[0];
    const float* embed = (const float*)d_in[1];
    const float* ema_embed = (const float*)d_in[2];
    const float* ema_num = (const float*)d_in[3];

    float* out = (float*)d_out;
    float* quantize = out;                                   // N*D
    float* embed_new = out + (size_t)N_TOTAL * D;            // K*D
    float* ema_num_new = embed_new + (size_t)K * D;          // K
    float* ema_embed_new = ema_num_new + K;                  // K*D

    char* ws = (char*)d_ws;
    unsigned int* ind = (unsigned int*)ws;                   // N u32
    unsigned int* bucket = ind + N_TOTAL;                    // N u32
    float* e2h = (float*)(bucket + N_TOTAL);                 // K f32
    float* denom = e2h + K;                                  // K f32
    unsigned int* counts = (unsigned int*)(denom + K);       // K u32
    unsigned int* offsets = counts + K;                      // K u32
    unsigned int* cursor = offsets + K;                      // K u32

    k_e2<<<K / 256, 256, 0, stream>>>(embed, e2h);
    k_argmax<<<N_TOTAL / BM, 256, 0, stream>>>(x, embed, e2h, ind);
    k_quant<<<(N_TOTAL * 32) / 256, 256, 0, stream>>>(ind, embed, quantize);

    k_zero<<<(K + 255) / 256, 256, 0, stream>>>(counts, cursor);
    k_count<<<N_TOTAL / 1024, 256, 0, stream>>>(ind, counts);
    k_scan<<<1, K, 0, stream>>>(counts, offsets, cursor);
    k_scatter<<<N_TOTAL / 256, 256, 0, stream>>>(ind, cursor, bucket);
    k_sum<<<K, 256, 0, stream>>>(bucket, offsets, counts, x, ema_num, ema_embed,
                                 ema_num_new, ema_embed_new);

    k_denom<<<1, K, 0, stream>>>(ema_num_new, denom);
    k_embednew<<<(K * D / 4) / 256, 256, 0, stream>>>(ema_embed_new, denom,
                                                      embed_new);
}

// Round 5
// 1342.214 us; speedup vs baseline: 2.5113x; 1.4927x over previous
//
#include <hip/hip_runtime.h>

#define N_TOTAL (8 * 32768)   // 262144 rows (2^18)
#define D 128
#define K 1024
#define DECAY 0.8f
#define EPS 1e-7f
#define MARGIN 4e-3f

typedef __attribute__((ext_vector_type(8))) short bf16x8;
typedef __attribute__((ext_vector_type(4))) float f32x4;
union B8 { uint4 u; bf16x8 b; };

// round-to-nearest-even f32 -> bf16 (bit trick), also returns the fp32 value
__device__ inline unsigned short f2b(float v, float& back) {
    unsigned int u = __float_as_uint(v);
    unsigned int r = (u + 0x7FFFu + ((u >> 16) & 1u)) >> 16;
    back = __uint_as_float(r << 16);
    return (unsigned short)r;
}

// ---------------------------------------------------------------------------
// K0: per code row: ehi/elo bf16 split of embed, e2h = 0.5*||e||^2 (exact fp32)
// 1024 blocks x 128 threads
// ---------------------------------------------------------------------------
__global__ __launch_bounds__(128) void k_prep(
    const float* __restrict__ embed, unsigned short* __restrict__ ehi,
    unsigned short* __restrict__ elo, float* __restrict__ e2h) {
    __shared__ float r2[2];
    int c = blockIdx.x, tid = threadIdx.x;
    float v = embed[(size_t)c * D + tid];
    float hb;
    unsigned short h = f2b(v, hb);
    float lb;
    unsigned short l = f2b(v - hb, lb);
    ehi[(size_t)c * D + tid] = h;
    elo[(size_t)c * D + tid] = l;
    float sq = v * v;
    for (int off = 32; off; off >>= 1) sq += __shfl_down(sq, off, 64);
    if ((tid & 63) == 0) r2[tid >> 6] = sq;
    __syncthreads();
    if (tid == 0) e2h[c] = 0.5f * (r2[0] + r2[1]);
}

// ---------------------------------------------------------------------------
// zero: counts, rescue_cnt, gsum (re-poisoned ws each launch)
// grid = K*D/256 = 512 blocks
// ---------------------------------------------------------------------------
__global__ __launch_bounds__(256) void k_zero(unsigned int* __restrict__ counts,
                                              unsigned int* __restrict__ rescue_cnt,
                                              float* __restrict__ gsum) {
    int i = blockIdx.x * 256 + threadIdx.x;
    if (i < K) counts[i] = 0u;
    if (i == 0) *rescue_cnt = 0u;
    gsum[i] = 0.f;  // grid exactly covers K*D
}

// ---------------------------------------------------------------------------
// K1: MFMA argmax. Block = 256 thr = 4 waves; wave owns 16 x-rows.
// D[code][xrow] = E.X^T via mfma_f32_16x16x32_bf16, 3 passes (hh, lh, hl).
// X frags (hi+lo, 4 K-chunks) in registers; E frags streamed (L2-resident).
// Per-lane top1/top2 over its 4 codes/tile; merge across lane quarters at end.
// Rows with top1-top2 < MARGIN appended to rescue list.
// ---------------------------------------------------------------------------
__global__ __launch_bounds__(256) void k_argmax_mfma(
    const float* __restrict__ x, const uint4* __restrict__ ehi4,
    const uint4* __restrict__ elo4, const float* __restrict__ e2h,
    unsigned int* __restrict__ ind, unsigned int* __restrict__ rescue_cnt,
    unsigned int* __restrict__ rescue_list) {
    __shared__ float e2s[K];
    int tid = threadIdx.x;
    for (int i = tid; i < K; i += 256) e2s[i] = e2h[i];

    int lane = tid & 63;
    int w = tid >> 6;
    int l15 = lane & 15, q = lane >> 4;
    size_t row = (size_t)blockIdx.x * 64 + w * 16 + l15;

    // load & split this lane's x fragments: chunk j covers k in [32j,32j+32),
    // lane holds k = 32j + 8q + 0..7  (same (row=lane&15, kchunk=lane>>4)
    // layout for A and B -> k-mapping consistent, dot exact)
    uint4 xh[4], xl[4];
    const float* xp = x + row * D + q * 8;
#pragma unroll
    for (int j = 0; j < 4; j++) {
        float4 f0 = *(const float4*)(xp + j * 32);
        float4 f1 = *(const float4*)(xp + j * 32 + 4);
        float fs[8] = {f0.x, f0.y, f0.z, f0.w, f1.x, f1.y, f1.z, f1.w};
        unsigned int hh[4], ll[4];
#pragma unroll
        for (int p = 0; p < 4; p++) {
            float b0, b1, d0, d1;
            unsigned short h0 = f2b(fs[2 * p], b0);
            unsigned short h1 = f2b(fs[2 * p + 1], b1);
            unsigned short s0 = f2b(fs[2 * p] - b0, d0);
            unsigned short s1 = f2b(fs[2 * p + 1] - b1, d1);
            hh[p] = (unsigned int)h0 | ((unsigned int)h1 << 16);
            ll[p] = (unsigned int)s0 | ((unsigned int)s1 << 16);
        }
        xh[j] = make_uint4(hh[0], hh[1], hh[2], hh[3]);
        xl[j] = make_uint4(ll[0], ll[1], ll[2], ll[3]);
    }
    __syncthreads();

    float t1 = -1e30f, t2 = -1e30f;
    unsigned int i1 = 0u;
    int ebase = l15 * 16 + q;  // uint4 index within a code-tile row group

#pragma unroll 2
    for (int ct = 0; ct < K / 16; ct++) {
        f32x4 acc = {0.f, 0.f, 0.f, 0.f};
        uint4 eh[4], el[4];
#pragma unroll
        for (int j = 0; j < 4; j++) {
            eh[j] = ehi4[ct * 256 + ebase + j * 4];
            el[j] = elo4[ct * 256 + ebase + j * 4];
        }
#pragma unroll
        for (int j = 0; j < 4; j++) {
            B8 a, b;
            a.u = eh[j]; b.u = xh[j];
            acc = __builtin_amdgcn_mfma_f32_16x16x32_bf16(a.b, b.b, acc, 0, 0, 0);
        }
#pragma unroll
        for (int j = 0; j < 4; j++) {
            B8 a, b;
            a.u = el[j]; b.u = xh[j];
            acc = __builtin_amdgcn_mfma_f32_16x16x32_bf16(a.b, b.b, acc, 0, 0, 0);
        }
#pragma unroll
        for (int j = 0; j < 4; j++) {
            B8 a, b;
            a.u = eh[j]; b.u = xl[j];
            acc = __builtin_amdgcn_mfma_f32_16x16x32_bf16(a.b, b.b, acc, 0, 0, 0);
        }
        // scores for this lane's 4 codes: code = ct*16 + q*4 + r
        float4 e2q = *(const float4*)&e2s[ct * 16 + q * 4];
        float vv[4] = {acc.x - e2q.x, acc.y - e2q.y, acc.z - e2q.z,
                       acc.w - e2q.w};
#pragma unroll
        for (int r = 0; r < 4; r++) {
            float u = vv[r];
            unsigned int c = (unsigned int)(ct * 16 + q * 4 + r);
            bool gt = u > t1;                 // strict: first-max wins ties
            t2 = fmaxf(t2, fminf(t1, u));
            t1 = fmaxf(t1, u);
            i1 = gt ? c : i1;
        }
    }

    // merge top-2 across the 4 lane-quarters sharing this x-row
#pragma unroll
    for (int off = 16; off <= 32; off <<= 1) {
        float t1p = __shfl_xor(t1, off);
        float t2p = __shfl_xor(t2, off);
        unsigned int i1p = (unsigned int)__shfl_xor((int)i1, off);
        float nt2 = fmaxf(fminf(t1, t1p), fmaxf(t2, t2p));
        unsigned int ni1 =
            (t1p > t1 || (t1p == t1 && i1p < i1)) ? i1p : i1;
        t1 = fmaxf(t1, t1p);
        t2 = nt2;
        i1 = ni1;
    }
    if (lane < 16) {
        ind[row] = i1;
        if (t1 - t2 < MARGIN) {
            unsigned int pos = atomicAdd(rescue_cnt, 1u);
            rescue_list[pos] = (unsigned int)row;
        }
    }
}

// ---------------------------------------------------------------------------
// K1b: exact fp32 rescore of flagged rows (expected: a few hundred)
// fixed grid; blocks stride the list; early exit if none
// ---------------------------------------------------------------------------
__global__ __launch_bounds__(256) void k_rescue(
    const unsigned int* __restrict__ rescue_cnt,
    const unsigned int* __restrict__ rescue_list, const float* __restrict__ x,
    const float* __restrict__ embed, const float* __restrict__ e2h,
    unsigned int* __restrict__ ind) {
    __shared__ float xr[D];
    __shared__ float bv[4];
    __shared__ unsigned int bi[4];
    unsigned int cnt = *rescue_cnt;
    int tid = threadIdx.x;
    for (unsigned int it = blockIdx.x; it < cnt; it += gridDim.x) {
        unsigned int row = rescue_list[it];
        __syncthreads();
        if (tid < D) xr[tid] = x[(size_t)row * D + tid];
        __syncthreads();
        float best = -1e30f;
        unsigned int besti = 0u;
        for (int c = tid; c < K; c += 256) {   // ascending -> strict > = first max
            const float* e = embed + (size_t)c * D;
            float s = 0.f;
            for (int d = 0; d < D; d += 4) {
                float4 xv = *(const float4*)&xr[d];
                float4 ev = *(const float4*)&e[d];
                s += xv.x * ev.x + xv.y * ev.y + xv.z * ev.z + xv.w * ev.w;
            }
            s -= e2h[c];
            if (s > best) { best = s; besti = (unsigned int)c; }
        }
        for (int off = 32; off; off >>= 1) {
            float ov = __shfl_down(best, off, 64);
            unsigned int oi = (unsigned int)__shfl_down((int)besti, off, 64);
            if (ov > best || (ov == best && oi < besti)) { best = ov; besti = oi; }
        }
        if ((tid & 63) == 0) { bv[tid >> 6] = best; bi[tid >> 6] = besti; }
        __syncthreads();
        if (tid == 0) {
            for (int wv = 1; wv < 4; wv++)
                if (bv[wv] > best || (bv[wv] == best && bi[wv] < besti)) {
                    best = bv[wv];
                    besti = bi[wv];
                }
            ind[row] = besti;
        }
    }
}

// ---------------------------------------------------------------------------
// K2: quantize[n][:] = embed[ind[n]][:]
// ---------------------------------------------------------------------------
__global__ __launch_bounds__(256) void k_quant(
    const unsigned int* __restrict__ ind, const float* __restrict__ embed,
    float* __restrict__ q) {
    size_t gid = (size_t)blockIdx.x * 256 + threadIdx.x;  // N*32 threads
    size_t n = gid >> 5;
    int d4 = (int)(gid & 31) << 2;
    unsigned int c = ind[n];
    *(float4*)&q[n * D + d4] = *(const float4*)&embed[(size_t)c * D + d4];
}

// ---------------------------------------------------------------------------
// histogram: 256 blocks x 256 threads, 4 entries/thread
// ---------------------------------------------------------------------------
__global__ __launch_bounds__(256) void k_count(
    const unsigned int* __restrict__ ind, unsigned int* __restrict__ counts) {
    __shared__ unsigned int hist[K];
    int tid = threadIdx.x;
    for (int i = tid; i < K; i += 256) hist[i] = 0u;
    __syncthreads();
    int base = blockIdx.x * 1024;
#pragma unroll
    for (int j = 0; j < 4; j++)
        atomicAdd(&hist[ind[base + j * 256 + tid]], 1u);
    __syncthreads();
    for (int i = tid; i < K; i += 256) {
        unsigned int h = hist[i];
        if (h) atomicAdd(&counts[i], h);
    }
}

// single block exclusive scan -> cursor
__global__ __launch_bounds__(1024) void k_scan(
    const unsigned int* __restrict__ counts, unsigned int* __restrict__ cursor) {
    __shared__ unsigned int tmp[K];
    int tid = threadIdx.x;
    unsigned int v = counts[tid];
    tmp[tid] = v;
    __syncthreads();
    for (int off = 1; off < K; off <<= 1) {
        unsigned int t = (tid >= off) ? tmp[tid - off] : 0u;
        __syncthreads();
        tmp[tid] += t;
        __syncthreads();
    }
    cursor[tid] = tmp[tid] - v;
}

// scatter: bucket[pos] = (n<<10) | code   (n < 2^18, code < 2^10)
__global__ __launch_bounds__(256) void k_scatter(
    const unsigned int* __restrict__ ind, unsigned int* __restrict__ cursor,
    unsigned int* __restrict__ bucket) {
    unsigned int n = blockIdx.x * 256 + threadIdx.x;
    unsigned int c = ind[n];
    unsigned int pos = atomicAdd(&cursor[c], 1u);
    bucket[pos] = (n << 10) | c;
}

// ---------------------------------------------------------------------------
// balanced segment sum: each block owns exactly 128 bucket entries (sorted by
// code); accumulate runs in registers (thread = one d), flush runs with
// coalesced f32 atomics. Load-balanced regardless of code popularity.
// ---------------------------------------------------------------------------
__global__ __launch_bounds__(128) void k_sum2(
    const unsigned int* __restrict__ bucket, const float* __restrict__ x,
    float* __restrict__ gsum) {
    __shared__ unsigned int ent[128];
    int tid = threadIdx.x;
    ent[tid] = bucket[blockIdx.x * 128 + tid];
    __syncthreads();
    float acc = 0.f;
    unsigned int cur = ent[0] & 1023u;
    for (int e = 0; e < 128; e++) {
        unsigned int pk = ent[e];          // uniform across block
        unsigned int c = pk & 1023u;
        unsigned int n = pk >> 10;
        if (c != cur) {                    // scalar branch (block-uniform)
            atomicAdd(&gsum[(size_t)cur * D + tid], acc);
            acc = 0.f;
            cur = c;
        }
        acc += x[(size_t)n * D + tid];
    }
    atomicAdd(&gsum[(size_t)cur * D + tid], acc);
}

// ema_embed_new / ema_num_new from gsum + counts
__global__ __launch_bounds__(256) void k_emafin(
    const float* __restrict__ gsum, const unsigned int* __restrict__ counts,
    const float* __restrict__ ema_num, const float* __restrict__ ema_embed,
    float* __restrict__ ema_num_new, float* __restrict__ ema_embed_new) {
    int gid = blockIdx.x * 256 + threadIdx.x;  // K*D threads
    ema_embed_new[gid] = DECAY * ema_embed[gid] + (1.0f - DECAY) * gsum[gid];
    if (gid < K)
        ema_num_new[gid] =
            DECAY * ema_num[gid] + (1.0f - DECAY) * (float)counts[gid];
}

// ---------------------------------------------------------------------------
// K4: total = sum(ema_num_new); denom[k] = (v+EPS)/(total+K*EPS)*total
// ---------------------------------------------------------------------------
__global__ __launch_bounds__(1024) void k_denom(
    const float* __restrict__ ema_num_new, float* __restrict__ denom) {
    __shared__ float red[16];
    int tid = threadIdx.x;
    float v = ema_num_new[tid];
    float s = v;
    for (int off = 32; off; off >>= 1) s += __shfl_down(s, off, 64);
    if ((tid & 63) == 0) red[tid >> 6] = s;
    __syncthreads();
    if (tid < 16) {
        float t = red[tid];
        for (int off = 8; off; off >>= 1) t += __shfl_down(t, off, 16);
        if (tid == 0) red[0] = t;
    }
    __syncthreads();
    float total = red[0];
    denom[tid] = (v + EPS) / (total + (float)K * EPS) * total;
}

// K5: embed_new = ema_embed_new / denom[k]
__global__ __launch_bounds__(256) void k_embednew(
    const float* __restrict__ ema_embed_new, const float* __restrict__ denom,
    float* __restrict__ embed_new) {
    int gid = blockIdx.x * 256 + threadIdx.x;  // K*D/4 threads
    int k = gid >> 5;
    int d4 = (gid & 31) << 2;
    float4 v = *(const float4*)&ema_embed_new[(size_t)k * D + d4];
    float s = denom[k];
    float4 o;
    o.x = v.x / s; o.y = v.y / s; o.z = v.z / s; o.w = v.w / s;
    *(float4*)&embed_new[(size_t)k * D + d4] = o;
}

// ---------------------------------------------------------------------------
extern "C" void kernel_launch(void* const* d_in, const int* in_sizes, int n_in,
                              void* d_out, int out_size, void* d_ws,
                              size_t ws_size, hipStream_t stream) {
    const float* x = (const float*)d_in[0];
    const float* embed = (const float*)d_in[1];
    const float* ema_embed = (const float*)d_in[2];
    const float* ema_num = (const float*)d_in[3];

    float* out = (float*)d_out;
    float* quantize = out;                                   // N*D
    float* embed_new = out + (size_t)N_TOTAL * D;            // K*D
    float* ema_num_new = embed_new + (size_t)K * D;          // K
    float* ema_embed_new = ema_num_new + K;                  // K*D

    char* ws = (char*)d_ws;
    unsigned int* ind = (unsigned int*)ws;                   // N u32 (1MB)
    unsigned int* bucket = ind + N_TOTAL;                    // N u32 (1MB)
    unsigned int* rescue_list = bucket + N_TOTAL;            // N u32 (1MB)
    unsigned short* ehi = (unsigned short*)(rescue_list + N_TOTAL);  // K*D u16
    unsigned short* elo = ehi + (size_t)K * D;               // K*D u16
    float* gsum = (float*)(elo + (size_t)K * D);             // K*D f32 (512KB)
    float* e2h = gsum + (size_t)K * D;                       // K f32
    float* denom = e2h + K;                                  // K f32
    unsigned int* counts = (unsigned int*)(denom + K);       // K u32
    unsigned int* cursor = counts + K;                       // K u32
    unsigned int* rescue_cnt = cursor + K;                   // 1 u32

    k_prep<<<K, 128, 0, stream>>>(embed, ehi, elo, e2h);
    k_zero<<<(K * D) / 256, 256, 0, stream>>>(counts, rescue_cnt, gsum);
    k_argmax_mfma<<<N_TOTAL / 64, 256, 0, stream>>>(
        x, (const uint4*)ehi, (const uint4*)elo, e2h, ind, rescue_cnt,
        rescue_list);
    k_rescue<<<256, 256, 0, stream>>>(rescue_cnt, rescue_list, x, embed, e2h,
                                      ind);
    k_quant<<<(N_TOTAL * 32) / 256, 256, 0, stream>>>(ind, embed, quantize);

    k_count<<<N_TOTAL / 1024, 256, 0, stream>>>(ind, counts);
    k_scan<<<1, K, 0, stream>>>(counts, cursor);
    k_scatter<<<N_TOTAL / 256, 256, 0, stream>>>(ind, cursor, bucket);
    k_sum2<<<N_TOTAL / 128, 128, 0, stream>>>(bucket, x, gsum);
    k_emafin<<<(K * D) / 256, 256, 0, stream>>>(gsum, counts, ema_num,
                                                ema_embed, ema_num_new,
                                                ema_embed_new);

    k_denom<<<1, K, 0, stream>>>(ema_num_new, denom);
    k_embednew<<<(K * D / 4) / 256, 256, 0, stream>>>(ema_embed_new, denom,
                                                      embed_new);
}

// Round 6
// 1326.786 us; speedup vs baseline: 2.5405x; 1.0116x over previous
//
#include <hip/hip_runtime.h>

#define N_TOTAL (8 * 32768)   // 262144 rows (2^18)
#define D 128
#define K 1024
#define DECAY 0.8f
#define EPS 1e-7f
#define MARGIN 4e-3f

typedef __attribute__((ext_vector_type(8))) short bf16x8;
typedef __attribute__((ext_vector_type(4))) float f32x4;
union B8 { uint4 u; bf16x8 b; };

// round-to-nearest-even f32 -> bf16 (bit trick), also returns the fp32 value
__device__ inline unsigned short f2b(float v, float& back) {
    unsigned int u = __float_as_uint(v);
    unsigned int r = (u + 0x7FFFu + ((u >> 16) & 1u)) >> 16;
    back = __uint_as_float(r << 16);
    return (unsigned short)r;
}

// ---------------------------------------------------------------------------
// K0: per code row: ehi/elo bf16 split of embed, e2h = 0.5*||e||^2 (exact fp32)
// ---------------------------------------------------------------------------
__global__ __launch_bounds__(128) void k_prep(
    const float* __restrict__ embed, unsigned short* __restrict__ ehi,
    unsigned short* __restrict__ elo, float* __restrict__ e2h) {
    __shared__ float r2[2];
    int c = blockIdx.x, tid = threadIdx.x;
    float v = embed[(size_t)c * D + tid];
    float hb;
    unsigned short h = f2b(v, hb);
    float lb;
    unsigned short l = f2b(v - hb, lb);
    ehi[(size_t)c * D + tid] = h;
    elo[(size_t)c * D + tid] = l;
    float sq = v * v;
    for (int off = 32; off; off >>= 1) sq += __shfl_down(sq, off, 64);
    if ((tid & 63) == 0) r2[tid >> 6] = sq;
    __syncthreads();
    if (tid == 0) e2h[c] = 0.5f * (r2[0] + r2[1]);
}

// ---------------------------------------------------------------------------
// zero: counts, rescue_cnt, gsum
// ---------------------------------------------------------------------------
__global__ __launch_bounds__(256) void k_zero(unsigned int* __restrict__ counts,
                                              unsigned int* __restrict__ rescue_cnt,
                                              float* __restrict__ gsum) {
    int i = blockIdx.x * 256 + threadIdx.x;
    if (i < K) counts[i] = 0u;
    if (i == 0) *rescue_cnt = 0u;
    gsum[i] = 0.f;  // grid exactly covers K*D
}

// ---------------------------------------------------------------------------
// K1: MFMA argmax. Block = 512 thr = 8 waves; wave owns 16 x-rows.
// D[code][xrow] = E.X^T via mfma_f32_16x16x32_bf16, 3 passes (hh, lh, hl).
// 4 independent acc chains (per K-chunk) + A/B register prefetch of E tiles.
// ---------------------------------------------------------------------------
#define MFMA(A, B, C) __builtin_amdgcn_mfma_f32_16x16x32_bf16((A), (B), (C), 0, 0, 0)

#define PASS(EHL, X, A0, A1, A2, A3)                        \
    {                                                       \
        B8 a_, b_;                                          \
        a_.u = EHL[0]; b_.u = X[0]; A0 = MFMA(a_.b, b_.b, A0); \
        a_.u = EHL[1]; b_.u = X[1]; A1 = MFMA(a_.b, b_.b, A1); \
        a_.u = EHL[2]; b_.u = X[2]; A2 = MFMA(a_.b, b_.b, A2); \
        a_.u = EHL[3]; b_.u = X[3]; A3 = MFMA(a_.b, b_.b, A3); \
    }

#define TILE(EH, EL, CT)                                                   \
    do {                                                                   \
        f32x4 a0 = {0.f, 0.f, 0.f, 0.f}, a1 = {0.f, 0.f, 0.f, 0.f};        \
        f32x4 a2 = {0.f, 0.f, 0.f, 0.f}, a3 = {0.f, 0.f, 0.f, 0.f};        \
        PASS(EH, xh, a0, a1, a2, a3);                                      \
        PASS(EL, xh, a0, a1, a2, a3);                                      \
        PASS(EH, xl, a0, a1, a2, a3);                                      \
        f32x4 sv = (a0 + a1) + (a2 + a3);                                  \
        float4 e2q = *(const float4*)&e2s[(CT) * 16 + q * 4];              \
        float vv[4] = {sv.x - e2q.x, sv.y - e2q.y, sv.z - e2q.z,           \
                       sv.w - e2q.w};                                      \
        _Pragma("unroll") for (int r = 0; r < 4; r++) {                    \
            float u = vv[r];                                               \
            unsigned int c = (unsigned int)((CT) * 16 + q * 4 + r);        \
            bool gt = u > t1;                                              \
            t2 = fmaxf(t2, fminf(t1, u));                                  \
            t1 = fmaxf(t1, u);                                             \
            i1 = gt ? c : i1;                                              \
        }                                                                  \
    } while (0)

__global__ __launch_bounds__(512) void k_argmax_mfma(
    const float* __restrict__ x, const uint4* __restrict__ ehi4,
    const uint4* __restrict__ elo4, const float* __restrict__ e2h,
    unsigned int* __restrict__ ind, unsigned int* __restrict__ rescue_cnt,
    unsigned int* __restrict__ rescue_list) {
    __shared__ float e2s[K];
    int tid = threadIdx.x;
    for (int i = tid; i < K; i += 512) e2s[i] = e2h[i];

    int lane = tid & 63;
    int w = tid >> 6;                 // 0..7
    int l15 = lane & 15, q = lane >> 4;
    size_t row = (size_t)blockIdx.x * 128 + w * 16 + l15;

    // load & split this lane's x fragments: chunk j covers k in [32j,32j+32),
    // lane holds k = 32j + 8q + 0..7 (same layout for A and B -> exact dot)
    uint4 xh[4], xl[4];
    const float* xp = x + row * D + q * 8;
#pragma unroll
    for (int j = 0; j < 4; j++) {
        float4 f0 = *(const float4*)(xp + j * 32);
        float4 f1 = *(const float4*)(xp + j * 32 + 4);
        float fs[8] = {f0.x, f0.y, f0.z, f0.w, f1.x, f1.y, f1.z, f1.w};
        unsigned int hh[4], ll[4];
#pragma unroll
        for (int p = 0; p < 4; p++) {
            float b0, b1, d0, d1;
            unsigned short h0 = f2b(fs[2 * p], b0);
            unsigned short h1 = f2b(fs[2 * p + 1], b1);
            unsigned short s0 = f2b(fs[2 * p] - b0, d0);
            unsigned short s1 = f2b(fs[2 * p + 1] - b1, d1);
            hh[p] = (unsigned int)h0 | ((unsigned int)h1 << 16);
            ll[p] = (unsigned int)s0 | ((unsigned int)s1 << 16);
        }
        xh[j] = make_uint4(hh[0], hh[1], hh[2], hh[3]);
        xl[j] = make_uint4(ll[0], ll[1], ll[2], ll[3]);
    }
    __syncthreads();

    float t1 = -1e30f, t2 = -1e30f;
    unsigned int i1 = 0u;
    int ebase = l15 * 16 + q;  // uint4 index within a code-tile row group

    uint4 ehA[4], elA[4], ehB[4], elB[4];
#pragma unroll
    for (int j = 0; j < 4; j++) {
        ehA[j] = ehi4[ebase + j * 4];
        elA[j] = elo4[ebase + j * 4];
    }

    for (int ct = 0; ct < K / 16; ct += 2) {
        // prefetch tile ct+1 into B while computing tile ct from A
#pragma unroll
        for (int j = 0; j < 4; j++) {
            ehB[j] = ehi4[(ct + 1) * 256 + ebase + j * 4];
            elB[j] = elo4[(ct + 1) * 256 + ebase + j * 4];
        }
        TILE(ehA, elA, ct);
        // prefetch tile ct+2 into A while computing tile ct+1 from B
        if (ct + 2 < K / 16) {
#pragma unroll
            for (int j = 0; j < 4; j++) {
                ehA[j] = ehi4[(ct + 2) * 256 + ebase + j * 4];
                elA[j] = elo4[(ct + 2) * 256 + ebase + j * 4];
            }
        }
        TILE(ehB, elB, ct + 1);
    }

    // merge top-2 across the 4 lane-quarters sharing this x-row
#pragma unroll
    for (int off = 16; off <= 32; off <<= 1) {
        float t1p = __shfl_xor(t1, off);
        float t2p = __shfl_xor(t2, off);
        unsigned int i1p = (unsigned int)__shfl_xor((int)i1, off);
        float nt2 = fmaxf(fminf(t1, t1p), fmaxf(t2, t2p));
        unsigned int ni1 = (t1p > t1 || (t1p == t1 && i1p < i1)) ? i1p : i1;
        t1 = fmaxf(t1, t1p);
        t2 = nt2;
        i1 = ni1;
    }
    if (lane < 16) {
        ind[row] = i1;
        if (t1 - t2 < MARGIN) {
            unsigned int pos = atomicAdd(rescue_cnt, 1u);
            rescue_list[pos] = (unsigned int)row;
        }
    }
}

// ---------------------------------------------------------------------------
// K1b: exact fp32 rescore of flagged rows
// ---------------------------------------------------------------------------
__global__ __launch_bounds__(256) void k_rescue(
    const unsigned int* __restrict__ rescue_cnt,
    const unsigned int* __restrict__ rescue_list, const float* __restrict__ x,
    const float* __restrict__ embed, const float* __restrict__ e2h,
    unsigned int* __restrict__ ind) {
    __shared__ float xr[D];
    __shared__ float bv[4];
    __shared__ unsigned int bi[4];
    unsigned int cnt = *rescue_cnt;
    int tid = threadIdx.x;
    for (unsigned int it = blockIdx.x; it < cnt; it += gridDim.x) {
        unsigned int row = rescue_list[it];
        __syncthreads();
        if (tid < D) xr[tid] = x[(size_t)row * D + tid];
        __syncthreads();
        float best = -1e30f;
        unsigned int besti = 0u;
        for (int c = tid; c < K; c += 256) {   // ascending -> strict > = first max
            const float* e = embed + (size_t)c * D;
            float s = 0.f;
            for (int d = 0; d < D; d += 4) {
                float4 xv = *(const float4*)&xr[d];
                float4 ev = *(const float4*)&e[d];
                s += xv.x * ev.x + xv.y * ev.y + xv.z * ev.z + xv.w * ev.w;
            }
            s -= e2h[c];
            if (s > best) { best = s; besti = (unsigned int)c; }
        }
        for (int off = 32; off; off >>= 1) {
            float ov = __shfl_down(best, off, 64);
            unsigned int oi = (unsigned int)__shfl_down((int)besti, off, 64);
            if (ov > best || (ov == best && oi < besti)) { best = ov; besti = oi; }
        }
        if ((tid & 63) == 0) { bv[tid >> 6] = best; bi[tid >> 6] = besti; }
        __syncthreads();
        if (tid == 0) {
            for (int wv = 1; wv < 4; wv++)
                if (bv[wv] > best || (bv[wv] == best && bi[wv] < besti)) {
                    best = bv[wv];
                    besti = bi[wv];
                }
            ind[row] = besti;
        }
    }
}

// ---------------------------------------------------------------------------
// K2: quantize[n][:] = embed[ind[n]][:]
// ---------------------------------------------------------------------------
__global__ __launch_bounds__(256) void k_quant(
    const unsigned int* __restrict__ ind, const float* __restrict__ embed,
    float* __restrict__ q) {
    size_t gid = (size_t)blockIdx.x * 256 + threadIdx.x;  // N*32 threads
    size_t n = gid >> 5;
    int d4 = (int)(gid & 31) << 2;
    unsigned int c = ind[n];
    *(float4*)&q[n * D + d4] = *(const float4*)&embed[(size_t)c * D + d4];
}

// ---------------------------------------------------------------------------
// histogram: 256 blocks x 256 threads, 4 entries/thread
// ---------------------------------------------------------------------------
__global__ __launch_bounds__(256) void k_count(
    const unsigned int* __restrict__ ind, unsigned int* __restrict__ counts) {
    __shared__ unsigned int hist[K];
    int tid = threadIdx.x;
    for (int i = tid; i < K; i += 256) hist[i] = 0u;
    __syncthreads();
    int base = blockIdx.x * 1024;
#pragma unroll
    for (int j = 0; j < 4; j++)
        atomicAdd(&hist[ind[base + j * 256 + tid]], 1u);
    __syncthreads();
    for (int i = tid; i < K; i += 256) {
        unsigned int h = hist[i];
        if (h) atomicAdd(&counts[i], h);
    }
}

// single block exclusive scan -> cursor
__global__ __launch_bounds__(1024) void k_scan(
    const unsigned int* __restrict__ counts, unsigned int* __restrict__ cursor) {
    __shared__ unsigned int tmp[K];
    int tid = threadIdx.x;
    unsigned int v = counts[tid];
    tmp[tid] = v;
    __syncthreads();
    for (int off = 1; off < K; off <<= 1) {
        unsigned int t = (tid >= off) ? tmp[tid - off] : 0u;
        __syncthreads();
        tmp[tid] += t;
        __syncthreads();
    }
    cursor[tid] = tmp[tid] - v;
}

// scatter: bucket[pos] = (n<<10) | code   (n < 2^18, code < 2^10)
__global__ __launch_bounds__(256) void k_scatter(
    const unsigned int* __restrict__ ind, unsigned int* __restrict__ cursor,
    unsigned int* __restrict__ bucket) {
    unsigned int n = blockIdx.x * 256 + threadIdx.x;
    unsigned int c = ind[n];
    unsigned int pos = atomicAdd(&cursor[c], 1u);
    bucket[pos] = (n << 10) | c;
}

// ---------------------------------------------------------------------------
// balanced segment sum: each block owns exactly 128 sorted bucket entries;
// run accumulation in registers, flush runs with coalesced f32 atomics.
// ---------------------------------------------------------------------------
__global__ __launch_bounds__(128) void k_sum2(
    const unsigned int* __restrict__ bucket, const float* __restrict__ x,
    float* __restrict__ gsum) {
    __shared__ unsigned int ent[128];
    int tid = threadIdx.x;
    ent[tid] = bucket[blockIdx.x * 128 + tid];
    __syncthreads();
    float acc = 0.f;
    unsigned int cur = ent[0] & 1023u;
    for (int e = 0; e < 128; e++) {
        unsigned int pk = ent[e];          // uniform across block
        unsigned int c = pk & 1023u;
        unsigned int n = pk >> 10;
        if (c != cur) {                    // block-uniform branch
            atomicAdd(&gsum[(size_t)cur * D + tid], acc);
            acc = 0.f;
            cur = c;
        }
        acc += x[(size_t)n * D + tid];
    }
    atomicAdd(&gsum[(size_t)cur * D + tid], acc);
}

// ema_embed_new / ema_num_new from gsum + counts
__global__ __launch_bounds__(256) void k_emafin(
    const float* __restrict__ gsum, const unsigned int* __restrict__ counts,
    const float* __restrict__ ema_num, const float* __restrict__ ema_embed,
    float* __restrict__ ema_num_new, float* __restrict__ ema_embed_new) {
    int gid = blockIdx.x * 256 + threadIdx.x;  // K*D threads
    ema_embed_new[gid] = DECAY * ema_embed[gid] + (1.0f - DECAY) * gsum[gid];
    if (gid < K)
        ema_num_new[gid] =
            DECAY * ema_num[gid] + (1.0f - DECAY) * (float)counts[gid];
}

// ---------------------------------------------------------------------------
// K4: total = sum(ema_num_new); denom[k] = (v+EPS)/(total+K*EPS)*total
// ---------------------------------------------------------------------------
__global__ __launch_bounds__(1024) void k_denom(
    const float* __restrict__ ema_num_new, float* __restrict__ denom) {
    __shared__ float red[16];
    int tid = threadIdx.x;
    float v = ema_num_new[tid];
    float s = v;
    for (int off = 32; off; off >>= 1) s += __shfl_down(s, off, 64);
    if ((tid & 63) == 0) red[tid >> 6] = s;
    __syncthreads();
    if (tid < 16) {
        float t = red[tid];
        for (int off = 8; off; off >>= 1) t += __shfl_down(t, off, 16);
        if (tid == 0) red[0] = t;
    }
    __syncthreads();
    float total = red[0];
    denom[tid] = (v + EPS) / (total + (float)K * EPS) * total;
}

// K5: embed_new = ema_embed_new / denom[k]
__global__ __launch_bounds__(256) void k_embednew(
    const float* __restrict__ ema_embed_new, const float* __restrict__ denom,
    float* __restrict__ embed_new) {
    int gid = blockIdx.x * 256 + threadIdx.x;  // K*D/4 threads
    int k = gid >> 5;
    int d4 = (gid & 31) << 2;
    float4 v = *(const float4*)&ema_embed_new[(size_t)k * D + d4];
    float s = denom[k];
    float4 o;
    o.x = v.x / s; o.y = v.y / s; o.z = v.z / s; o.w = v.w / s;
    *(float4*)&embed_new[(size_t)k * D + d4] = o;
}

// ---------------------------------------------------------------------------
extern "C" void kernel_launch(void* const* d_in, const int* in_sizes, int n_in,
                              void* d_out, int out_size, void* d_ws,
                              size_t ws_size, hipStream_t stream) {
    const float* x = (const float*)d_in[0];
    const float* embed = (const float*)d_in[1];
    const float* ema_embed = (const float*)d_in[2];
    const float* ema_num = (const float*)d_in[3];

    float* out = (float*)d_out;
    float* quantize = out;                                   // N*D
    float* embed_new = out + (size_t)N_TOTAL * D;            // K*D
    float* ema_num_new = embed_new + (size_t)K * D;          // K
    float* ema_embed_new = ema_num_new + K;                  // K*D

    char* ws = (char*)d_ws;
    unsigned int* ind = (unsigned int*)ws;                   // N u32 (1MB)
    unsigned int* bucket = ind + N_TOTAL;                    // N u32 (1MB)
    unsigned int* rescue_list = bucket + N_TOTAL;            // N u32 (1MB)
    unsigned short* ehi = (unsigned short*)(rescue_list + N_TOTAL);  // K*D u16
    unsigned short* elo = ehi + (size_t)K * D;               // K*D u16
    float* gsum = (float*)(elo + (size_t)K * D);             // K*D f32 (512KB)
    float* e2h = gsum + (size_t)K * D;                       // K f32
    float* denom = e2h + K;                                  // K f32
    unsigned int* counts = (unsigned int*)(denom + K);       // K u32
    unsigned int* cursor = counts + K;                       // K u32
    unsigned int* rescue_cnt = cursor + K;                   // 1 u32

    k_prep<<<K, 128, 0, stream>>>(embed, ehi, elo, e2h);
    k_zero<<<(K * D) / 256, 256, 0, stream>>>(counts, rescue_cnt, gsum);
    k_argmax_mfma<<<N_TOTAL / 128, 512, 0, stream>>>(
        x, (const uint4*)ehi, (const uint4*)elo, e2h, ind, rescue_cnt,
        rescue_list);
    k_rescue<<<256, 256, 0, stream>>>(rescue_cnt, rescue_list, x, embed, e2h,
                                      ind);
    k_quant<<<(N_TOTAL * 32) / 256, 256, 0, stream>>>(ind, embed, quantize);

    k_count<<<N_TOTAL / 1024, 256, 0, stream>>>(ind, counts);
    k_scan<<<1, K, 0, stream>>>(counts, cursor);
    k_scatter<<<N_TOTAL / 256, 256, 0, stream>>>(ind, cursor, bucket);
    k_sum2<<<N_TOTAL / 128, 128, 0, stream>>>(bucket, x, gsum);
    k_emafin<<<(K * D) / 256, 256, 0, stream>>>(gsum, counts, ema_num,
                                                ema_embed, ema_num_new,
                                                ema_embed_new);

    k_denom<<<1, K, 0, stream>>>(ema_num_new, denom);
    k_embednew<<<(K * D / 4) / 256, 256, 0, stream>>>(ema_embed_new, denom,
                                                      embed_new);
}

// Round 11
// 633.463 us; speedup vs baseline: 5.3211x; 2.0945x over previous
//
#include <hip/hip_runtime.h>

#define N_TOTAL (8 * 32768)   // 262144 rows (2^18)
#define D 128
#define K 1024
#define DECAY 0.8f
#define EPS 1e-7f
#define MARGIN 4e-3f

typedef __attribute__((ext_vector_type(8))) short bf16x8;
typedef __attribute__((ext_vector_type(4))) float f32x4;
union B8 { uint4 u; bf16x8 b; };

#define MFMA(A, B, C) __builtin_amdgcn_mfma_f32_16x16x32_bf16((A), (B), (C), 0, 0, 0)

#define PASS(EHL, X, A0, A1, A2, A3)                        \
    {                                                       \
        B8 a_, b_;                                          \
        a_.u = EHL[0]; b_.u = X[0]; A0 = MFMA(a_.b, b_.b, A0); \
        a_.u = EHL[1]; b_.u = X[1]; A1 = MFMA(a_.b, b_.b, A1); \
        a_.u = EHL[2]; b_.u = X[2]; A2 = MFMA(a_.b, b_.b, A2); \
        a_.u = EHL[3]; b_.u = X[3]; A3 = MFMA(a_.b, b_.b, A3); \
    }

// round-to-nearest-even f32 -> bf16 (bit trick), also returns the fp32 value
__device__ inline unsigned short f2b(float v, float& back) {
    unsigned int u = __float_as_uint(v);
    unsigned int r = (u + 0x7FFFu + ((u >> 16) & 1u)) >> 16;
    back = __uint_as_float(r << 16);
    return (unsigned short)r;
}

// ---------------------------------------------------------------------------
// K0 (round-5 proven): ehi/elo bf16 split of embed + e2h = 0.5*||e||^2 fp32
// ---------------------------------------------------------------------------
__global__ __launch_bounds__(128) void k_prep(
    const float* __restrict__ embed, unsigned short* __restrict__ ehi,
    unsigned short* __restrict__ elo, float* __restrict__ e2h) {
    __shared__ float r2[2];
    int c = blockIdx.x, tid = threadIdx.x;
    float v = embed[(size_t)c * D + tid];
    float hb;
    unsigned short h = f2b(v, hb);
    float lb;
    unsigned short l = f2b(v - hb, lb);
    ehi[(size_t)c * D + tid] = h;
    elo[(size_t)c * D + tid] = l;
    float sq = v * v;
    for (int off = 32; off; off >>= 1) sq += __shfl_down(sq, off, 64);
    if ((tid & 63) == 0) r2[tid >> 6] = sq;
    __syncthreads();
    if (tid == 0) e2h[c] = 0.5f * (r2[0] + r2[1]);
}

__global__ __launch_bounds__(256) void k_zero(unsigned int* __restrict__ counts,
                                              unsigned int* __restrict__ rescue_cnt,
                                              float* __restrict__ gsum) {
    int i = blockIdx.x * 256 + threadIdx.x;
    if (i < K) counts[i] = 0u;
    if (i == 0) *rescue_cnt = 0u;
    gsum[i] = 0.f;  // grid exactly covers K*D
}

// ---------------------------------------------------------------------------
// K1: 3-pass hi/lo MFMA screen (r5/r6-proven numerics & layout), with E
// staged per-block in PADDED LDS (plain ds_write staging, double-buffered).
// Block = 512 thr = 8 waves; wave owns 16 x-rows; supertile = 64 codes.
// LDS row stride 17 uint4 -> worst 2-way bank aliasing (free).
// ---------------------------------------------------------------------------
__global__ __launch_bounds__(512, 2) void k_screen(
    const float* __restrict__ x, const uint4* __restrict__ ehi4,
    const uint4* __restrict__ elo4, const float* __restrict__ e2h,
    unsigned int* __restrict__ ind, unsigned int* __restrict__ rescue_cnt,
    unsigned int* __restrict__ rescue_list) {
    __shared__ uint4 ebh[2][64 * 17];   // 2 x 17 KB
    __shared__ uint4 ebl[2][64 * 17];   // 2 x 17 KB
    __shared__ float e2s[K];            // 4 KB

    int tid = threadIdx.x;
    int w = tid >> 6, lane = tid & 63;
    int l15 = lane & 15, q = lane >> 4;
    size_t row = (size_t)blockIdx.x * 128 + w * 16 + l15;

    for (int i = tid; i < K; i += 512) e2s[i] = e2h[i];

    // ---- X hi/lo fragments: direct global->reg (r5-proven):
    // lane holds rows w*16+l15, k = 32j + 8q + 0..7
    uint4 xh[4], xl[4];
    const float* xp = x + row * D + q * 8;
#pragma unroll
    for (int j = 0; j < 4; j++) {
        float4 f0 = *(const float4*)(xp + j * 32);
        float4 f1 = *(const float4*)(xp + j * 32 + 4);
        float fs[8] = {f0.x, f0.y, f0.z, f0.w, f1.x, f1.y, f1.z, f1.w};
        unsigned int hh[4], ll[4];
#pragma unroll
        for (int p = 0; p < 4; p++) {
            float b0, b1, d0, d1;
            unsigned short h0 = f2b(fs[2 * p], b0);
            unsigned short h1 = f2b(fs[2 * p + 1], b1);
            unsigned short s0 = f2b(fs[2 * p] - b0, d0);
            unsigned short s1 = f2b(fs[2 * p + 1] - b1, d1);
            hh[p] = (unsigned int)h0 | ((unsigned int)h1 << 16);
            ll[p] = (unsigned int)s0 | ((unsigned int)s1 << 16);
        }
        xh[j] = make_uint4(hh[0], hh[1], hh[2], hh[3]);
        xl[j] = make_uint4(ll[0], ll[1], ll[2], ll[3]);
    }

    // ---- prologue: stage supertile 0 (64 codes x 16 uint4 per array)
    {
        int i0 = tid, i1 = tid + 512;
        int c0 = i0 >> 4, u0 = i0 & 15;
        int c1 = i1 >> 4, u1 = i1 & 15;
        ebh[0][c0 * 17 + u0] = ehi4[i0];
        ebl[0][c0 * 17 + u0] = elo4[i0];
        ebh[0][c1 * 17 + u1] = ehi4[i1];
        ebl[0][c1 * 17 + u1] = elo4[i1];
    }
    __syncthreads();

    float t1 = -1e30f, t2 = -1e30f;
    unsigned int i1g = 0u;

    for (int st = 0; st < 16; st++) {
        int b = st & 1;
        // issue next supertile's global loads early (write to LDS after compute)
        uint4 rh0, rl0, rh1, rl1;
        if (st < 15) {
            const uint4* gh = ehi4 + (size_t)(st + 1) * 1024;
            const uint4* gl = elo4 + (size_t)(st + 1) * 1024;
            rh0 = gh[tid];
            rl0 = gl[tid];
            rh1 = gh[tid + 512];
            rl1 = gl[tid + 512];
        }

#pragma unroll
        for (int ct = 0; ct < 4; ct++) {
            uint4 eh[4], el[4];
            int cr = (ct * 16 + l15) * 17;
#pragma unroll
            for (int j = 0; j < 4; j++) {
                eh[j] = ebh[b][cr + 4 * j + q];
                el[j] = ebl[b][cr + 4 * j + q];
            }
            f32x4 a0 = {0.f, 0.f, 0.f, 0.f}, a1 = {0.f, 0.f, 0.f, 0.f};
            f32x4 a2 = {0.f, 0.f, 0.f, 0.f}, a3 = {0.f, 0.f, 0.f, 0.f};
            PASS(eh, xh, a0, a1, a2, a3);
            PASS(el, xh, a0, a1, a2, a3);
            PASS(eh, xl, a0, a1, a2, a3);
            f32x4 sv = (a0 + a1) + (a2 + a3);
            int cbase = st * 64 + ct * 16 + q * 4;
            float4 e2q = *(const float4*)&e2s[cbase];
            float vv[4] = {sv.x - e2q.x, sv.y - e2q.y, sv.z - e2q.z,
                           sv.w - e2q.w};
#pragma unroll
            for (int r = 0; r < 4; r++) {
                float u = vv[r];
                unsigned int c = (unsigned int)(cbase + r);
                bool gt = u > t1;
                t2 = fmaxf(t2, fminf(t1, u));
                t1 = fmaxf(t1, u);
                i1g = gt ? c : i1g;
            }
        }

        if (st < 15) {
            int i0 = tid, i1 = tid + 512;
            int c0 = i0 >> 4, u0 = i0 & 15;
            int c1 = i1 >> 4, u1 = i1 & 15;
            ebh[b ^ 1][c0 * 17 + u0] = rh0;
            ebl[b ^ 1][c0 * 17 + u0] = rl0;
            ebh[b ^ 1][c1 * 17 + u1] = rh1;
            ebl[b ^ 1][c1 * 17 + u1] = rl1;
        }
        __syncthreads();
    }

    // merge top-2 across the 4 lane-quarters sharing this x-row (r5-proven)
#pragma unroll
    for (int off = 16; off <= 32; off <<= 1) {
        float t1p = __shfl_xor(t1, off);
        float t2p = __shfl_xor(t2, off);
        unsigned int i1p = (unsigned int)__shfl_xor((int)i1g, off);
        float nt2 = fmaxf(fminf(t1, t1p), fmaxf(t2, t2p));
        unsigned int ni1 = (t1p > t1 || (t1p == t1 && i1p < i1g)) ? i1p : i1g;
        t1 = fmaxf(t1, t1p);
        t2 = nt2;
        i1g = ni1;
    }
    if (lane < 16) {
        ind[row] = i1g;
        if (t1 - t2 < MARGIN) {
            unsigned int pos = atomicAdd(rescue_cnt, 1u);
            rescue_list[pos] = (unsigned int)row;
        }
    }
}

// ---------------------------------------------------------------------------
// K1b (r5-proven): exact fp32 rescore of flagged rows (expected: hundreds)
// ---------------------------------------------------------------------------
__global__ __launch_bounds__(256) void k_rescue(
    const unsigned int* __restrict__ rescue_cnt,
    const unsigned int* __restrict__ rescue_list, const float* __restrict__ x,
    const float* __restrict__ embed, const float* __restrict__ e2h,
    unsigned int* __restrict__ ind) {
    __shared__ float xr[D];
    __shared__ float bv[4];
    __shared__ unsigned int bi[4];
    unsigned int cnt = *rescue_cnt;
    int tid = threadIdx.x;
    for (unsigned int it = blockIdx.x; it < cnt; it += gridDim.x) {
        unsigned int row = rescue_list[it];
        __syncthreads();
        if (tid < D) xr[tid] = x[(size_t)row * D + tid];
        __syncthreads();
        float best = -1e30f;
        unsigned int besti = 0u;
        for (int c = tid; c < K; c += 256) {   // ascending -> strict > = first max
            const float* e = embed + (size_t)c * D;
            float s = 0.f;
            for (int d = 0; d < D; d += 4) {
                float4 xv = *(const float4*)&xr[d];
                float4 ev = *(const float4*)&e[d];
                s += xv.x * ev.x + xv.y * ev.y + xv.z * ev.z + xv.w * ev.w;
            }
            s -= e2h[c];
            if (s > best) { best = s; besti = (unsigned int)c; }
        }
        for (int off = 32; off; off >>= 1) {
            float ov = __shfl_down(best, off, 64);
            unsigned int oi = (unsigned int)__shfl_down((int)besti, off, 64);
            if (ov > best || (ov == best && oi < besti)) { best = ov; besti = oi; }
        }
        if ((tid & 63) == 0) { bv[tid >> 6] = best; bi[tid >> 6] = besti; }
        __syncthreads();
        if (tid == 0) {
            for (int wv = 1; wv < 4; wv++)
                if (bv[wv] > best || (bv[wv] == best && bi[wv] < besti)) {
                    best = bv[wv];
                    besti = bi[wv];
                }
            ind[row] = besti;
        }
    }
}

// ---------------------------------------------------------------------------
// K2: quantize[n][:] = embed[ind[n]][:]  (runs after rescue)
// ---------------------------------------------------------------------------
__global__ __launch_bounds__(256) void k_quant(
    const unsigned int* __restrict__ ind, const float* __restrict__ embed,
    float* __restrict__ q) {
    size_t gid = (size_t)blockIdx.x * 256 + threadIdx.x;  // N*32 threads
    size_t n = gid >> 5;
    int d4 = (int)(gid & 31) << 2;
    unsigned int c = ind[n];
    *(float4*)&q[n * D + d4] = *(const float4*)&embed[(size_t)c * D + d4];
}

// ---------------------------------------------------------------------------
// histogram (after rescue so counts use final ind)
// ---------------------------------------------------------------------------
__global__ __launch_bounds__(256) void k_count(
    const unsigned int* __restrict__ ind, unsigned int* __restrict__ counts) {
    __shared__ unsigned int hist[K];
    int tid = threadIdx.x;
    for (int i = tid; i < K; i += 256) hist[i] = 0u;
    __syncthreads();
    int base = blockIdx.x * 1024;
#pragma unroll
    for (int j = 0; j < 4; j++)
        atomicAdd(&hist[ind[base + j * 256 + tid]], 1u);
    __syncthreads();
    for (int i = tid; i < K; i += 256) {
        unsigned int h = hist[i];
        if (h) atomicAdd(&counts[i], h);
    }
}

__global__ __launch_bounds__(1024) void k_scan(
    const unsigned int* __restrict__ counts, unsigned int* __restrict__ cursor) {
    __shared__ unsigned int tmp[K];
    int tid = threadIdx.x;
    unsigned int v = counts[tid];
    tmp[tid] = v;
    __syncthreads();
    for (int off = 1; off < K; off <<= 1) {
        unsigned int t = (tid >= off) ? tmp[tid - off] : 0u;
        __syncthreads();
        tmp[tid] += t;
        __syncthreads();
    }
    cursor[tid] = tmp[tid] - v;
}

__global__ __launch_bounds__(256) void k_scatter(
    const unsigned int* __restrict__ ind, unsigned int* __restrict__ cursor,
    unsigned int* __restrict__ bucket) {
    unsigned int n = blockIdx.x * 256 + threadIdx.x;
    unsigned int c = ind[n];
    unsigned int pos = atomicAdd(&cursor[c], 1u);
    bucket[pos] = (n << 10) | c;
}

__global__ __launch_bounds__(128) void k_sum2(
    const unsigned int* __restrict__ bucket, const float* __restrict__ x,
    float* __restrict__ gsum) {
    __shared__ unsigned int ent[128];
    int tid = threadIdx.x;
    ent[tid] = bucket[blockIdx.x * 128 + tid];
    __syncthreads();
    float acc = 0.f;
    unsigned int cur = ent[0] & 1023u;
    for (int e = 0; e < 128; e++) {
        unsigned int pk = ent[e];          // uniform across block
        unsigned int c = pk & 1023u;
        unsigned int n = pk >> 10;
        if (c != cur) {                    // block-uniform branch
            atomicAdd(&gsum[(size_t)cur * D + tid], acc);
            acc = 0.f;
            cur = c;
        }
        acc += x[(size_t)n * D + tid];
    }
    atomicAdd(&gsum[(size_t)cur * D + tid], acc);
}

__global__ __launch_bounds__(256) void k_emafin(
    const float* __restrict__ gsum, const unsigned int* __restrict__ counts,
    const float* __restrict__ ema_num, const float* __restrict__ ema_embed,
    float* __restrict__ ema_num_new, float* __restrict__ ema_embed_new) {
    int gid = blockIdx.x * 256 + threadIdx.x;  // K*D threads
    ema_embed_new[gid] = DECAY * ema_embed[gid] + (1.0f - DECAY) * gsum[gid];
    if (gid < K)
        ema_num_new[gid] =
            DECAY * ema_num[gid] + (1.0f - DECAY) * (float)counts[gid];
}

__global__ __launch_bounds__(1024) void k_denom(
    const float* __restrict__ ema_num_new, float* __restrict__ denom) {
    __shared__ float red[16];
    int tid = threadIdx.x;
    float v = ema_num_new[tid];
    float s = v;
    for (int off = 32; off; off >>= 1) s += __shfl_down(s, off, 64);
    if ((tid & 63) == 0) red[tid >> 6] = s;
    __syncthreads();
    if (tid < 16) {
        float t = red[tid];
        for (int off = 8; off; off >>= 1) t += __shfl_down(t, off, 16);
        if (tid == 0) red[0] = t;
    }
    __syncthreads();
    float total = red[0];
    denom[tid] = (v + EPS) / (total + (float)K * EPS) * total;
}

__global__ __launch_bounds__(256) void k_embednew(
    const float* __restrict__ ema_embed_new, const float* __restrict__ denom,
    float* __restrict__ embed_new) {
    int gid = blockIdx.x * 256 + threadIdx.x;  // K*D/4 threads
    int k = gid >> 5;
    int d4 = (gid & 31) << 2;
    float4 v = *(const float4*)&ema_embed_new[(size_t)k * D + d4];
    float s = denom[k];
    float4 o;
    o.x = v.x / s; o.y = v.y / s; o.z = v.z / s; o.w = v.w / s;
    *(float4*)&embed_new[(size_t)k * D + d4] = o;
}

// ---------------------------------------------------------------------------
extern "C" void kernel_launch(void* const* d_in, const int* in_sizes, int n_in,
                              void* d_out, int out_size, void* d_ws,
                              size_t ws_size, hipStream_t stream) {
    const float* x = (const float*)d_in[0];
    const float* embed = (const float*)d_in[1];
    const float* ema_embed = (const float*)d_in[2];
    const float* ema_num = (const float*)d_in[3];

    float* out = (float*)d_out;
    float* quantize = out;                                   // N*D
    float* embed_new = out + (size_t)N_TOTAL * D;            // K*D
    float* ema_num_new = embed_new + (size_t)K * D;          // K
    float* ema_embed_new = ema_num_new + K;                  // K*D

    char* ws = (char*)d_ws;
    unsigned int* ind = (unsigned int*)ws;                   // N u32
    unsigned int* bucket = ind + N_TOTAL;                    // N u32
    unsigned int* rescue_list = bucket + N_TOTAL;            // N u32
    unsigned short* ehi = (unsigned short*)(rescue_list + N_TOTAL);  // K*D u16
    unsigned short* elo = ehi + (size_t)K * D;               // K*D u16
    float* gsum = (float*)(elo + (size_t)K * D);             // K*D f32
    float* e2h = gsum + (size_t)K * D;                       // K f32
    float* denom = e2h + K;                                  // K f32
    unsigned int* counts = (unsigned int*)(denom + K);       // K u32
    unsigned int* cursor = counts + K;                       // K u32
    unsigned int* rescue_cnt = cursor + K;                   // 1 u32

    k_prep<<<K, 128, 0, stream>>>(embed, ehi, elo, e2h);
    k_zero<<<(K * D) / 256, 256, 0, stream>>>(counts, rescue_cnt, gsum);
    k_screen<<<N_TOTAL / 128, 512, 0, stream>>>(
        x, (const uint4*)ehi, (const uint4*)elo, e2h, ind, rescue_cnt,
        rescue_list);
    k_rescue<<<256, 256, 0, stream>>>(rescue_cnt, rescue_list, x, embed, e2h,
                                      ind);
    k_quant<<<(N_TOTAL * 32) / 256, 256, 0, stream>>>(ind, embed, quantize);
    k_count<<<N_TOTAL / 1024, 256, 0, stream>>>(ind, counts);
    k_scan<<<1, K, 0, stream>>>(counts, cursor);
    k_scatter<<<N_TOTAL / 256, 256, 0, stream>>>(ind, cursor, bucket);
    k_sum2<<<N_TOTAL / 128, 128, 0, stream>>>(bucket, x, gsum);
    k_emafin<<<(K * D) / 256, 256, 0, stream>>>(gsum, counts, ema_num,
                                                ema_embed, ema_num_new,
                                                ema_embed_new);
    k_denom<<<1, K, 0, stream>>>(ema_num_new, denom);
    k_embednew<<<(K * D / 4) / 256, 256, 0, stream>>>(ema_embed_new, denom,
                                                      embed_new);
}